// Round 10
// baseline (2741.796 us; speedup 1.0000x reference)
//
#include <hip/hip_runtime.h>

#define N_NODES 50000
#define N_EDGES 800000
#define IN_CH 128
#define HID 32
#define OUT_CH 10
#define N_GRAPHS 256
#define PR_ITERS 8
#define NEUMANN_K 4      // ||cWA||~=0.125 -> truncation ~3e-5 rel; measured absmax 0.5 (1 bf16 ulp)
#define N_GROUPS (N_NODES / 8)   // 6250 groups of 8 nodes
#define PR_BLOCKS 1250           // 6250 = 1250*5 exact balance; 5 blocks/CU -> all resident
#define BIAS_BLOCKS 1024
#define NSHARD 32

// ---------------------------------------------------------------------------
// Cayley: W = 0.5 * (I+S)^{-1} (I-S),  S = B - B^T.  Stores W TRANSPOSED:
// Wt[k*32+h] = W[h][k]  (so LDS reads sWt[k*32+lane] are conflict-free).
// ---------------------------------------------------------------------------
__global__ __launch_bounds__(256) void cayley_kernel(const float* __restrict__ B,
                                                     float* __restrict__ Wt) {
    __shared__ float aug[32][65];
    __shared__ float sf[32];
    int tid = threadIdx.x;
    for (int idx = tid; idx < 32 * 64; idx += 256) {
        int r = idx >> 6, c = idx & 63;
        float val;
        if (c < 32) {
            float s = B[r * 32 + c] - B[c * 32 + r];
            val = (r == c ? 1.f : 0.f) + s;
        } else {
            int cc = c - 32;
            float s = B[r * 32 + cc] - B[cc * 32 + r];
            val = (r == cc ? 1.f : 0.f) - s;
        }
        aug[r][c] = val;
    }
    __syncthreads();
    for (int p = 0; p < 32; ++p) {
        float piv = aug[p][p];
        __syncthreads();
        if (tid < 64) aug[p][tid] /= piv;
        __syncthreads();
        if (tid < 32) sf[tid] = aug[tid][p];
        __syncthreads();
        for (int idx = tid; idx < 32 * 64; idx += 256) {
            int r = idx >> 6, c = idx & 63;
            if (r != p) aug[r][c] -= sf[r] * aug[p][c];
        }
        __syncthreads();
    }
    for (int idx = tid; idx < 1024; idx += 256) {
        int k = idx >> 5, h = idx & 31;
        Wt[idx] = 0.5f * aug[h][32 + k];  // (1-m)=0.5 scale
    }
}

// ---------------------------------------------------------------------------
// bias[n][h] = dot(x[n,:128], enc_w[:,h]) + enc_b[h], stored (N, 32)
// ---------------------------------------------------------------------------
__global__ __launch_bounds__(256) void bias_kernel(const float* __restrict__ x,
                                                   const float* __restrict__ enc_w,
                                                   const float* __restrict__ enc_b,
                                                   float* __restrict__ bias) {
    __shared__ float sW[IN_CH * HID];  // 16 KB
    int tid = threadIdx.x;
    for (int i = tid; i < IN_CH * HID; i += 256) sW[i] = enc_w[i];
    __syncthreads();
    int lane = tid & 31;
    int hw = tid >> 5;
    float b0 = enc_b[lane];
    for (int grp = blockIdx.x; grp < N_GROUPS; grp += BIAS_BLOCKS) {
        int n = grp * 8 + hw;
        float4 v = ((const float4*)(x + (size_t)n * IN_CH))[lane];
        float acc = b0;
#pragma unroll
        for (int k = 0; k < 32; ++k) {
            acc += __shfl(v.x, k, 32) * sW[(4 * k + 0) * HID + lane];
            acc += __shfl(v.y, k, 32) * sW[(4 * k + 1) * HID + lane];
            acc += __shfl(v.z, k, 32) * sW[(4 * k + 2) * HID + lane];
            acc += __shfl(v.w, k, 32) * sW[(4 * k + 3) * HID + lane];
        }
        bias[(size_t)n * HID + lane] = acc;
    }
}

// ---------------------------------------------------------------------------
// CSR build: histogram over destination (col), scan, scatter of packed int2
// ---------------------------------------------------------------------------
__global__ __launch_bounds__(256) void hist_kernel(const int* __restrict__ ei,
                                                   int* __restrict__ deg) {
    int e = blockIdx.x * 256 + threadIdx.x;
    if (e < N_EDGES) atomicAdd(&deg[ei[N_EDGES + e]], 1);
}

__global__ __launch_bounds__(1024) void scan_kernel(const int* __restrict__ deg,
                                                    int* __restrict__ col_ptr,
                                                    int* __restrict__ cursor) {
    __shared__ int swave[16];
    __shared__ int spre[17];
    int tid = threadIdx.x;
    int lane = tid & 63;
    int wid = tid >> 6;
    int run = 0;
    for (int base = 0; base < N_NODES; base += 1024) {
        int i = base + tid;
        int v = (i < N_NODES) ? deg[i] : 0;
        int incl = v;
#pragma unroll
        for (int off = 1; off < 64; off <<= 1) {
            int t = __shfl_up(incl, off, 64);
            if (lane >= off) incl += t;
        }
        if (lane == 63) swave[wid] = incl;
        __syncthreads();
        if (tid == 0) {
            int s = 0;
            for (int w = 0; w < 16; ++w) { spre[w] = s; s += swave[w]; }
            spre[16] = s;
        }
        __syncthreads();
        int excl = run + spre[wid] + (incl - v);
        if (i < N_NODES) { col_ptr[i] = excl; cursor[i] = excl; }
        run += spre[16];
        __syncthreads();
    }
    if (tid == 0) col_ptr[N_NODES] = run;
}

__global__ __launch_bounds__(256) void scatter_kernel(const int* __restrict__ ei,
                                                      const float* __restrict__ ew,
                                                      int* __restrict__ cursor,
                                                      int2* __restrict__ edata) {
    int e = blockIdx.x * 256 + threadIdx.x;
    if (e >= N_EDGES) return;
    int c = ei[N_EDGES + e];
    int pos = atomicAdd(&cursor[c], 1);
    int2 md;
    md.x = ei[e] * (HID * 4);              // byte offset of source row
    md.y = __float_as_int(ew[e]);
    edata[pos] = md;
}

// ---------------------------------------------------------------------------
// Device-scope grid barrier (sharded arrivals + flag). __threadfence() is a
// device(agent)-scope full fence -> covers cross-XCD visibility (G16).
// Monotonic counters: no reset races. Safe only because all PR_BLOCKS are
// co-resident (launch_bounds contract: 1250 <= 5 blocks/CU * 256 CU).
// ---------------------------------------------------------------------------
__device__ __forceinline__ void gbar(unsigned* shards, unsigned* flag, unsigned b) {
    __syncthreads();
    if (threadIdx.x == 0) {
        __hip_atomic_fetch_add(shards + ((blockIdx.x & (NSHARD - 1)) << 5), 1u,
                               __ATOMIC_RELEASE, __HIP_MEMORY_SCOPE_AGENT);
        if (blockIdx.x == 0) {
            const unsigned target = b * (unsigned)PR_BLOCKS;
            for (;;) {
                unsigned sum = 0;
#pragma unroll
                for (int s = 0; s < NSHARD; ++s)
                    sum += __hip_atomic_load(shards + (s << 5), __ATOMIC_RELAXED,
                                             __HIP_MEMORY_SCOPE_AGENT);
                if (sum >= target) break;
                __builtin_amdgcn_s_sleep(2);
            }
            __threadfence();
            __hip_atomic_store(flag, b, __ATOMIC_RELEASE, __HIP_MEMORY_SCOPE_AGENT);
        } else {
            while (__hip_atomic_load(flag, __ATOMIC_RELAXED, __HIP_MEMORY_SCOPE_AGENT) < b)
                __builtin_amdgcn_s_sleep(16);
            __threadfence();
        }
    }
    __syncthreads();
}

// ---------------------------------------------------------------------------
// Fused PR kernel: 8 x (init + 4 Neumann steps) + pool, one launch.
// Each thread owns 5 (node, lane) slots (perfect balance: 6250 = 1250*5),
// so acc/u12/bias live entirely in registers; only t ping-pongs via global.
// Buffer schedule per iter: init->A, s0 A->B, s1 B->A, s2 A->B, s3 reads B
// (no write); swap after every step returns cur to A for the next init, so
// init's A-writes never race trailing s3 readers of B.
// ---------------------------------------------------------------------------
__global__ __launch_bounds__(256, 5) void pr_kernel(
        const float* __restrict__ bias, const int* __restrict__ col_ptr,
        const int2* __restrict__ edata, const float* __restrict__ Wt,
        float* __restrict__ tA, float* __restrict__ tB,
        const int* __restrict__ batch, float* __restrict__ pooled,
        unsigned* __restrict__ shards, unsigned* __restrict__ flag) {
    __shared__ float sWt[1024];
    int tid = threadIdx.x;
    for (int i = tid; i < 1024; i += 256) sWt[i] = Wt[i];
    __syncthreads();
    int lane = tid & 31;
    int hw = tid >> 5;
    int laneb = lane * 4;

    int idxb[5], ss[5], ee[5];
    float biasr[5], accr[5], u12r[5];
#pragma unroll
    for (int i = 0; i < 5; ++i) {
        int n = (blockIdx.x + i * PR_BLOCKS) * 8 + hw;
        idxb[i] = n * (HID * 4) + laneb;
        ss[i] = col_ptr[n];
        ee[i] = col_ptr[n + 1];
        biasr[i] = bias[(size_t)n * HID + lane];
    }
    char* ca = (char*)tA;
    char* cb = (char*)tB;
    unsigned bnum = 0;

    for (int it = 0; it < PR_ITERS; ++it) {
        // ----- INIT phase (node-local, register state) -----
#pragma unroll
        for (int i = 0; i < 5; ++i) {
            float v0;
            if (it == 0) {
                u12r[i] = 0.f;
                v0 = biasr[i];
            } else {
                float u = accr[i] - u12r[i];
                float z = fmaxf(u, 0.f);
                float un = 2.f * z - u;
                u12r[i] = un;
                v0 = un + biasr[i];
            }
            accr[i] = v0;
            float t = 0.f;
#pragma unroll
            for (int k2 = 0; k2 < 32; ++k2) t += sWt[k2 * 32 + lane] * __shfl(v0, k2, 32);
            *(float*)(ca + idxb[i]) = t;
        }
        gbar(shards, flag, ++bnum);

        // ----- Neumann steps -----
        for (int k = 0; k < NEUMANN_K; ++k) {
            bool wr = (k < NEUMANN_K - 1);
#pragma unroll
            for (int i = 0; i < 5; ++i) {
                int s = ss[i], e = ee[i];
                float g0 = 0.f, g1 = 0.f, g2 = 0.f, g3 = 0.f;
                float g4 = 0.f, g5 = 0.f, g6 = 0.f, g7 = 0.f;
                for (int base = s; base < e; base += 32) {
                    int rem = e - base;
                    int cnt = rem < 32 ? rem : 32;
                    int2 md = make_int2(0, 0);
                    if (lane < cnt) md = edata[base + lane];
                    int j = 0;
                    for (; j + 8 <= cnt; j += 8) {
                        int o0 = __shfl(md.x, j + 0, 32); float w0 = __int_as_float(__shfl(md.y, j + 0, 32));
                        int o1 = __shfl(md.x, j + 1, 32); float w1 = __int_as_float(__shfl(md.y, j + 1, 32));
                        int o2 = __shfl(md.x, j + 2, 32); float w2 = __int_as_float(__shfl(md.y, j + 2, 32));
                        int o3 = __shfl(md.x, j + 3, 32); float w3 = __int_as_float(__shfl(md.y, j + 3, 32));
                        int o4 = __shfl(md.x, j + 4, 32); float w4 = __int_as_float(__shfl(md.y, j + 4, 32));
                        int o5 = __shfl(md.x, j + 5, 32); float w5 = __int_as_float(__shfl(md.y, j + 5, 32));
                        int o6 = __shfl(md.x, j + 6, 32); float w6 = __int_as_float(__shfl(md.y, j + 6, 32));
                        int o7 = __shfl(md.x, j + 7, 32); float w7 = __int_as_float(__shfl(md.y, j + 7, 32));
                        float t0 = *(const float*)(ca + o0 + laneb);
                        float t1 = *(const float*)(ca + o1 + laneb);
                        float t2 = *(const float*)(ca + o2 + laneb);
                        float t3 = *(const float*)(ca + o3 + laneb);
                        float t4 = *(const float*)(ca + o4 + laneb);
                        float t5 = *(const float*)(ca + o5 + laneb);
                        float t6 = *(const float*)(ca + o6 + laneb);
                        float t7 = *(const float*)(ca + o7 + laneb);
                        g0 = fmaf(w0, t0, g0); g1 = fmaf(w1, t1, g1);
                        g2 = fmaf(w2, t2, g2); g3 = fmaf(w3, t3, g3);
                        g4 = fmaf(w4, t4, g4); g5 = fmaf(w5, t5, g5);
                        g6 = fmaf(w6, t6, g6); g7 = fmaf(w7, t7, g7);
                    }
                    for (; j < cnt; ++j) {
                        int o = __shfl(md.x, j, 32);
                        float w = __int_as_float(__shfl(md.y, j, 32));
                        g0 = fmaf(w, *(const float*)(ca + o + laneb), g0);
                    }
                }
                float term = 0.5f * (((g0 + g1) + (g2 + g3)) + ((g4 + g5) + (g6 + g7)));
                accr[i] += term;
                if (wr) {
                    float t = 0.f;
#pragma unroll
                    for (int k2 = 0; k2 < 32; ++k2) t += sWt[k2 * 32 + lane] * __shfl(term, k2, 32);
                    *(float*)(cb + idxb[i]) = t;
                }
            }
            if (wr) gbar(shards, flag, ++bnum);
            char* tmp = ca; ca = cb; cb = tmp;
        }
    }

    // ----- Pool: z = relu(acc - u12), segment-sum by graph -----
#pragma unroll
    for (int i = 0; i < 5; ++i) {
        int n = (blockIdx.x + i * PR_BLOCKS) * 8 + hw;
        float z = fmaxf(accr[i] - u12r[i], 0.f);
        int g = batch[n];
        atomicAdd(&pooled[g * HID + lane], z);
    }
}

__global__ __launch_bounds__(256) void decode_kernel(const float* __restrict__ pooled,
                                                     const float* __restrict__ dec_w,
                                                     float* __restrict__ out) {
    int idx = blockIdx.x * 256 + threadIdx.x;
    if (idx >= N_GRAPHS * OUT_CH) return;
    int g = idx / OUT_CH, o = idx % OUT_CH;
    float s = 0.f;
#pragma unroll
    for (int k = 0; k < HID; ++k) s += pooled[g * HID + k] * dec_w[k * OUT_CH + o];
    out[idx] = s;
}

// ---------------------------------------------------------------------------
extern "C" void kernel_launch(void* const* d_in, const int* in_sizes, int n_in,
                              void* d_out, int out_size, void* d_ws, size_t ws_size,
                              hipStream_t stream) {
    const float* x        = (const float*)d_in[0];
    const int*   ei       = (const int*)d_in[1];
    const float* ew       = (const float*)d_in[2];
    const int*   batch    = (const int*)d_in[4];
    const float* enc_w    = (const float*)d_in[5];
    const float* enc_b    = (const float*)d_in[6];
    const float* dec_w    = (const float*)d_in[7];
    const float* cayley_B = (const float*)d_in[8];
    float* out = (float*)d_out;

    char* ws = (char*)d_ws;
    size_t off = 0;
    auto alloc = [&](size_t bytes) {
        void* p = ws + off;
        off = (off + bytes + 255) & ~(size_t)255;
        return p;
    };
    float*    bias    = (float*)alloc((size_t)N_NODES * HID * 4);
    float*    tA      = (float*)alloc((size_t)N_NODES * HID * 4);
    float*    tB      = (float*)alloc((size_t)N_NODES * HID * 4);
    float*    Wt      = (float*)alloc(1024 * 4);
    float*    pooled  = (float*)alloc((size_t)N_GRAPHS * HID * 4);
    int*      deg     = (int*)alloc((size_t)N_NODES * 4);
    int*      col_ptr = (int*)alloc((size_t)(N_NODES + 1) * 4);
    int*      cursor  = (int*)alloc((size_t)N_NODES * 4);
    int2*     edata   = (int2*)alloc((size_t)N_EDGES * 8);
    unsigned* barrier = (unsigned*)alloc(8192);   // 32 shards*128B + flag line

    unsigned* shards = barrier;
    unsigned* flag   = barrier + (NSHARD << 5);   // next 128B line

    const int EDGE_BLOCKS = (N_EDGES + 255) / 256;   // 3125

    (void)hipMemsetAsync(deg, 0, (size_t)N_NODES * 4, stream);
    (void)hipMemsetAsync(pooled, 0, (size_t)N_GRAPHS * HID * 4, stream);
    (void)hipMemsetAsync(barrier, 0, 8192, stream);

    hist_kernel<<<EDGE_BLOCKS, 256, 0, stream>>>(ei, deg);
    scan_kernel<<<1, 1024, 0, stream>>>(deg, col_ptr, cursor);
    scatter_kernel<<<EDGE_BLOCKS, 256, 0, stream>>>(ei, ew, cursor, edata);
    cayley_kernel<<<1, 256, 0, stream>>>(cayley_B, Wt);
    bias_kernel<<<BIAS_BLOCKS, 256, 0, stream>>>(x, enc_w, enc_b, bias);

    pr_kernel<<<PR_BLOCKS, 256, 0, stream>>>(bias, col_ptr, edata, Wt, tA, tB,
                                             batch, pooled, shards, flag);

    decode_kernel<<<(N_GRAPHS * OUT_CH + 255) / 256, 256, 0, stream>>>(pooled, dec_w, out);
}

// Round 15
// 1390.667 us; speedup vs baseline: 1.9716x; 1.9716x over previous
//
#include <hip/hip_runtime.h>

#define N_NODES 50000
#define N_EDGES 800000
#define IN_CH 128
#define HID 32
#define OUT_CH 10
#define N_GRAPHS 256
#define PR_ITERS 8
#define NEUMANN_K 4   // K=4 measured absmax 0.5; K=3 would ~4x that -> keep 4
#define N_GROUPS (N_NODES / 8)   // 6250 groups of 8 nodes
#define STEP_BLOCKS 2048         // 8 blocks/CU resident -> full wave occupancy
#define BIAS_BLOCKS 1024

// t rows stored as 32 x bf16 = 64 B: t fits per-XCD L2 (3.2 MB < 4 MB),
// gather lines halve. Round-to-nearest-even float->bf16:
__device__ __forceinline__ unsigned short f2bf(float f) {
    unsigned u = __float_as_uint(f);
    u += 0x7FFFu + ((u >> 16) & 1u);
    return (unsigned short)(u >> 16);
}
__device__ __forceinline__ float bf2f(unsigned short us) {
    return __uint_as_float((unsigned)us << 16);
}

// ---------------------------------------------------------------------------
// Cayley: W = 0.5 * (I+S)^{-1} (I-S),  S = B - B^T.  Stores W TRANSPOSED:
// Wt[k*32+h] = W[h][k]  (so LDS reads sWt[k*32+lane] are conflict-free).
// ---------------------------------------------------------------------------
__global__ __launch_bounds__(256) void cayley_kernel(const float* __restrict__ B,
                                                     float* __restrict__ Wt) {
    __shared__ float aug[32][65];
    __shared__ float sf[32];
    int tid = threadIdx.x;
    for (int idx = tid; idx < 32 * 64; idx += 256) {
        int r = idx >> 6, c = idx & 63;
        float val;
        if (c < 32) {
            float s = B[r * 32 + c] - B[c * 32 + r];
            val = (r == c ? 1.f : 0.f) + s;
        } else {
            int cc = c - 32;
            float s = B[r * 32 + cc] - B[cc * 32 + r];
            val = (r == cc ? 1.f : 0.f) - s;
        }
        aug[r][c] = val;
    }
    __syncthreads();
    for (int p = 0; p < 32; ++p) {
        float piv = aug[p][p];
        __syncthreads();
        if (tid < 64) aug[p][tid] /= piv;
        __syncthreads();
        if (tid < 32) sf[tid] = aug[tid][p];
        __syncthreads();
        for (int idx = tid; idx < 32 * 64; idx += 256) {
            int r = idx >> 6, c = idx & 63;
            if (r != p) aug[r][c] -= sf[r] * aug[p][c];
        }
        __syncthreads();
    }
    for (int idx = tid; idx < 1024; idx += 256) {
        int k = idx >> 5, h = idx & 31;
        Wt[idx] = 0.5f * aug[h][32 + k];  // (1-m)=0.5 scale
    }
}

// ---------------------------------------------------------------------------
// bias[n][h] = dot(x[n,:128], enc_w[:,h]) + enc_b[h], stored (N, 32)
// ---------------------------------------------------------------------------
__global__ __launch_bounds__(256) void bias_kernel(const float* __restrict__ x,
                                                   const float* __restrict__ enc_w,
                                                   const float* __restrict__ enc_b,
                                                   float* __restrict__ bias) {
    __shared__ float sW[IN_CH * HID];  // 16 KB
    int tid = threadIdx.x;
    for (int i = tid; i < IN_CH * HID; i += 256) sW[i] = enc_w[i];
    __syncthreads();
    int lane = tid & 31;
    int hw = tid >> 5;
    float b0 = enc_b[lane];
    for (int grp = blockIdx.x; grp < N_GROUPS; grp += BIAS_BLOCKS) {
        int n = grp * 8 + hw;
        float4 v = ((const float4*)(x + (size_t)n * IN_CH))[lane];
        float acc = b0;
#pragma unroll
        for (int k = 0; k < 32; ++k) {
            acc += __shfl(v.x, k, 32) * sW[(4 * k + 0) * HID + lane];
            acc += __shfl(v.y, k, 32) * sW[(4 * k + 1) * HID + lane];
            acc += __shfl(v.z, k, 32) * sW[(4 * k + 2) * HID + lane];
            acc += __shfl(v.w, k, 32) * sW[(4 * k + 3) * HID + lane];
        }
        bias[(size_t)n * HID + lane] = acc;
    }
}

// ---------------------------------------------------------------------------
// CSR build: histogram over destination (col), scan, scatter of packed int2
// edata[i] = { src_node * 64 (byte offset into bf16 t), float_bits(weight) }
// ---------------------------------------------------------------------------
__global__ __launch_bounds__(256) void hist_kernel(const int* __restrict__ ei,
                                                   int* __restrict__ deg) {
    int e = blockIdx.x * 256 + threadIdx.x;
    if (e < N_EDGES) atomicAdd(&deg[ei[N_EDGES + e]], 1);
}

__global__ __launch_bounds__(1024) void scan_kernel(const int* __restrict__ deg,
                                                    int* __restrict__ col_ptr,
                                                    int* __restrict__ cursor) {
    __shared__ int swave[16];
    __shared__ int spre[17];
    int tid = threadIdx.x;
    int lane = tid & 63;
    int wid = tid >> 6;
    int run = 0;
    for (int base = 0; base < N_NODES; base += 1024) {
        int i = base + tid;
        int v = (i < N_NODES) ? deg[i] : 0;
        int incl = v;
#pragma unroll
        for (int off = 1; off < 64; off <<= 1) {
            int t = __shfl_up(incl, off, 64);
            if (lane >= off) incl += t;
        }
        if (lane == 63) swave[wid] = incl;
        __syncthreads();
        if (tid == 0) {
            int s = 0;
            for (int w = 0; w < 16; ++w) { spre[w] = s; s += swave[w]; }
            spre[16] = s;
        }
        __syncthreads();
        int excl = run + spre[wid] + (incl - v);
        if (i < N_NODES) { col_ptr[i] = excl; cursor[i] = excl; }
        run += spre[16];
        __syncthreads();
    }
    if (tid == 0) col_ptr[N_NODES] = run;
}

__global__ __launch_bounds__(256) void scatter_kernel(const int* __restrict__ ei,
                                                      const float* __restrict__ ew,
                                                      int* __restrict__ cursor,
                                                      int2* __restrict__ edata) {
    int e = blockIdx.x * 256 + threadIdx.x;
    if (e >= N_EDGES) return;
    int c = ei[N_EDGES + e];
    int pos = atomicAdd(&cursor[c], 1);
    int2 md;
    md.x = ei[e] * (HID * 2);              // byte offset of bf16 source row
    md.y = __float_as_int(ew[e]);
    edata[pos] = md;
}

// ---------------------------------------------------------------------------
// INIT (per PR iteration), grid-stride; writes t0 as bf16
// ---------------------------------------------------------------------------
__global__ __launch_bounds__(256) void init_kernel(const float* __restrict__ bias,
                                                   float* __restrict__ acc,
                                                   float* __restrict__ u12,
                                                   unsigned short* __restrict__ t0,
                                                   const float* __restrict__ Wt,
                                                   int first) {
    __shared__ float sWt[1024];
    int tid = threadIdx.x;
    for (int i = tid; i < 1024; i += 256) sWt[i] = Wt[i];
    __syncthreads();
    int lane = tid & 31;
    int hw = tid >> 5;
    for (int grp = blockIdx.x; grp < N_GROUPS; grp += STEP_BLOCKS) {
        int n = grp * 8 + hw;
        size_t idx = (size_t)n * HID + lane;
        float v0;
        if (first) {
            u12[idx] = 0.f;
            v0 = bias[idx];
        } else {
            float a = acc[idx];
            float up = u12[idx];
            float u = a - up;
            float z = fmaxf(u, 0.f);
            float un = 2.f * z - u;
            u12[idx] = un;
            v0 = un + bias[idx];
        }
        acc[idx] = v0;
        float t = 0.f;
#pragma unroll
        for (int k = 0; k < 32; ++k) t += sWt[k * 32 + lane] * __shfl(v0, k, 32);
        t0[idx] = f2bf(t);
    }
}

// ---------------------------------------------------------------------------
// STEP (one Neumann term): term[n] = 0.5 * sum_e w_e * t_in[src_e]
//                          acc[n] += term ; t_out[n] = W * term
// t stored bf16 (64B rows, L2-resident). Half-wave loads 32 edges' metadata
// in ONE coalesced int2 load, then unroll-8 broadcast loop issues 8
// independent 2B gathers (latency hiding).
// ---------------------------------------------------------------------------
__global__ __launch_bounds__(256) void step_kernel(const unsigned short* __restrict__ t_in,
                                                   unsigned short* __restrict__ t_out,
                                                   float* __restrict__ acc,
                                                   const int* __restrict__ col_ptr,
                                                   const int2* __restrict__ edata,
                                                   const float* __restrict__ Wt) {
    __shared__ float sWt[1024];
    int tid = threadIdx.x;
    for (int i = tid; i < 1024; i += 256) sWt[i] = Wt[i];
    __syncthreads();
    int lane = tid & 31;
    int hw = tid >> 5;
    const char* tb = (const char*)t_in;
    int laneb = lane * 2;
    for (int grp = blockIdx.x; grp < N_GROUPS; grp += STEP_BLOCKS) {
        int n = grp * 8 + hw;
        int s = col_ptr[n], e = col_ptr[n + 1];
        float g0 = 0.f, g1 = 0.f, g2 = 0.f, g3 = 0.f;
        float g4 = 0.f, g5 = 0.f, g6 = 0.f, g7 = 0.f;
        for (int base = s; base < e; base += 32) {
            int rem = e - base;
            int cnt = rem < 32 ? rem : 32;
            int2 md = make_int2(0, 0);
            if (lane < cnt) md = edata[base + lane];
            int j = 0;
            for (; j + 8 <= cnt; j += 8) {
                int o0 = __shfl(md.x, j + 0, 32); float w0 = __int_as_float(__shfl(md.y, j + 0, 32));
                int o1 = __shfl(md.x, j + 1, 32); float w1 = __int_as_float(__shfl(md.y, j + 1, 32));
                int o2 = __shfl(md.x, j + 2, 32); float w2 = __int_as_float(__shfl(md.y, j + 2, 32));
                int o3 = __shfl(md.x, j + 3, 32); float w3 = __int_as_float(__shfl(md.y, j + 3, 32));
                int o4 = __shfl(md.x, j + 4, 32); float w4 = __int_as_float(__shfl(md.y, j + 4, 32));
                int o5 = __shfl(md.x, j + 5, 32); float w5 = __int_as_float(__shfl(md.y, j + 5, 32));
                int o6 = __shfl(md.x, j + 6, 32); float w6 = __int_as_float(__shfl(md.y, j + 6, 32));
                int o7 = __shfl(md.x, j + 7, 32); float w7 = __int_as_float(__shfl(md.y, j + 7, 32));
                unsigned short t0 = *(const unsigned short*)(tb + o0 + laneb);
                unsigned short t1 = *(const unsigned short*)(tb + o1 + laneb);
                unsigned short t2 = *(const unsigned short*)(tb + o2 + laneb);
                unsigned short t3 = *(const unsigned short*)(tb + o3 + laneb);
                unsigned short t4 = *(const unsigned short*)(tb + o4 + laneb);
                unsigned short t5 = *(const unsigned short*)(tb + o5 + laneb);
                unsigned short t6 = *(const unsigned short*)(tb + o6 + laneb);
                unsigned short t7 = *(const unsigned short*)(tb + o7 + laneb);
                g0 = fmaf(w0, bf2f(t0), g0); g1 = fmaf(w1, bf2f(t1), g1);
                g2 = fmaf(w2, bf2f(t2), g2); g3 = fmaf(w3, bf2f(t3), g3);
                g4 = fmaf(w4, bf2f(t4), g4); g5 = fmaf(w5, bf2f(t5), g5);
                g6 = fmaf(w6, bf2f(t6), g6); g7 = fmaf(w7, bf2f(t7), g7);
            }
            for (; j < cnt; ++j) {
                int o = __shfl(md.x, j, 32);
                float w = __int_as_float(__shfl(md.y, j, 32));
                g0 = fmaf(w, bf2f(*(const unsigned short*)(tb + o + laneb)), g0);
            }
        }
        float g = ((g0 + g1) + (g2 + g3)) + ((g4 + g5) + (g6 + g7));
        float term = 0.5f * g;  // c = ALPHA/(1+ALPHA) = 0.5
        size_t idx = (size_t)n * HID + lane;
        acc[idx] += term;
        float t = 0.f;
#pragma unroll
        for (int k = 0; k < 32; ++k) t += sWt[k * 32 + lane] * __shfl(term, k, 32);
        t_out[idx] = f2bf(t);
    }
}

// ---------------------------------------------------------------------------
// Pool: z = relu(acc - u12); pooled[batch[n]] += z
// ---------------------------------------------------------------------------
__global__ __launch_bounds__(256) void pool_kernel(const float* __restrict__ acc,
                                                   const float* __restrict__ u12,
                                                   const int* __restrict__ batch,
                                                   float* __restrict__ pooled) {
    int tid = threadIdx.x;
    int lane = tid & 31;
    int hw = blockIdx.x * 8 + (tid >> 5);
    int n0 = hw * 8;
    float sum = 0.f;
    int curg = -1;
    for (int j = 0; j < 8; ++j) {
        int n = n0 + j;
        if (n >= N_NODES) break;
        int g = batch[n];
        size_t idx = (size_t)n * HID + lane;
        float z = fmaxf(acc[idx] - u12[idx], 0.f);
        if (g != curg) {
            if (curg >= 0) atomicAdd(&pooled[curg * HID + lane], sum);
            sum = 0.f;
            curg = g;
        }
        sum += z;
    }
    if (curg >= 0) atomicAdd(&pooled[curg * HID + lane], sum);
}

__global__ __launch_bounds__(256) void decode_kernel(const float* __restrict__ pooled,
                                                     const float* __restrict__ dec_w,
                                                     float* __restrict__ out) {
    int idx = blockIdx.x * 256 + threadIdx.x;
    if (idx >= N_GRAPHS * OUT_CH) return;
    int g = idx / OUT_CH, o = idx % OUT_CH;
    float s = 0.f;
#pragma unroll
    for (int k = 0; k < HID; ++k) s += pooled[g * HID + k] * dec_w[k * OUT_CH + o];
    out[idx] = s;
}

// ---------------------------------------------------------------------------
extern "C" void kernel_launch(void* const* d_in, const int* in_sizes, int n_in,
                              void* d_out, int out_size, void* d_ws, size_t ws_size,
                              hipStream_t stream) {
    const float* x        = (const float*)d_in[0];
    const int*   ei       = (const int*)d_in[1];
    const float* ew       = (const float*)d_in[2];
    const int*   batch    = (const int*)d_in[4];
    const float* enc_w    = (const float*)d_in[5];
    const float* enc_b    = (const float*)d_in[6];
    const float* dec_w    = (const float*)d_in[7];
    const float* cayley_B = (const float*)d_in[8];
    float* out = (float*)d_out;

    char* ws = (char*)d_ws;
    size_t off = 0;
    auto alloc = [&](size_t bytes) {
        void* p = ws + off;
        off = (off + bytes + 255) & ~(size_t)255;
        return p;
    };
    float*          bias    = (float*)alloc((size_t)N_NODES * HID * 4);
    float*          acc     = (float*)alloc((size_t)N_NODES * HID * 4);
    float*          u12     = (float*)alloc((size_t)N_NODES * HID * 4);
    unsigned short* tA      = (unsigned short*)alloc((size_t)N_NODES * HID * 2);
    unsigned short* tB      = (unsigned short*)alloc((size_t)N_NODES * HID * 2);
    float*          Wt      = (float*)alloc(1024 * 4);
    float*          pooled  = (float*)alloc((size_t)N_GRAPHS * HID * 4);
    int*            deg     = (int*)alloc((size_t)N_NODES * 4);
    int*            col_ptr = (int*)alloc((size_t)(N_NODES + 1) * 4);
    int*            cursor  = (int*)alloc((size_t)N_NODES * 4);
    int2*           edata   = (int2*)alloc((size_t)N_EDGES * 8);

    const int EDGE_BLOCKS = (N_EDGES + 255) / 256;   // 3125
    const int POOL_BLOCKS = ((N_NODES + 7) / 8 + 7) / 8;  // 782

    (void)hipMemsetAsync(deg, 0, (size_t)N_NODES * 4, stream);
    (void)hipMemsetAsync(pooled, 0, (size_t)N_GRAPHS * HID * 4, stream);

    hist_kernel<<<EDGE_BLOCKS, 256, 0, stream>>>(ei, deg);
    scan_kernel<<<1, 1024, 0, stream>>>(deg, col_ptr, cursor);
    scatter_kernel<<<EDGE_BLOCKS, 256, 0, stream>>>(ei, ew, cursor, edata);
    cayley_kernel<<<1, 256, 0, stream>>>(cayley_B, Wt);
    bias_kernel<<<BIAS_BLOCKS, 256, 0, stream>>>(x, enc_w, enc_b, bias);

    unsigned short* ta = tA;
    unsigned short* tb = tB;
    for (int it = 0; it < PR_ITERS; ++it) {
        init_kernel<<<STEP_BLOCKS, 256, 0, stream>>>(bias, acc, u12, ta, Wt, it == 0 ? 1 : 0);
        for (int k = 0; k < NEUMANN_K; ++k) {
            step_kernel<<<STEP_BLOCKS, 256, 0, stream>>>(ta, tb, acc, col_ptr, edata, Wt);
            unsigned short* tmp = ta; ta = tb; tb = tmp;
        }
    }

    pool_kernel<<<POOL_BLOCKS, 256, 0, stream>>>(acc, u12, batch, pooled);
    decode_kernel<<<(N_GRAPHS * OUT_CH + 255) / 256, 256, 0, stream>>>(pooled, dec_w, out);
}